// Round 4
// baseline (375.196 us; speedup 1.0000x reference)
//
#include <hip/hip_runtime.h>
#include <hip/hip_bf16.h>

// ---------- types ----------
typedef short bf16x8 __attribute__((ext_vector_type(8)));
typedef float f32x4 __attribute__((ext_vector_type(4)));

#define NB 4
#define C 256
#define HW 4096
#define NROWS (NB * HW)   // 16384
#define EPSF 1e-5f

// ---------- helpers ----------
__device__ __forceinline__ unsigned short f2bf(float f) {
    unsigned int u = __float_as_uint(f);
    unsigned int r = u + 0x7fffu + ((u >> 16) & 1u);
    return (unsigned short)(r >> 16);
}
__device__ __forceinline__ float bf2f(unsigned int h) {
    return __uint_as_float(h << 16);
}
__device__ __forceinline__ void unpack8(uint4 u, float* v) {
    unsigned int w0 = u.x, w1 = u.y, w2 = u.z, w3 = u.w;
    v[0] = bf2f(w0 & 0xffffu); v[1] = bf2f(w0 >> 16);
    v[2] = bf2f(w1 & 0xffffu); v[3] = bf2f(w1 >> 16);
    v[4] = bf2f(w2 & 0xffffu); v[5] = bf2f(w2 >> 16);
    v[6] = bf2f(w3 & 0xffffu); v[7] = bf2f(w3 >> 16);
}
__device__ __forceinline__ float waveReduceSum(float v) {
    for (int off = 32; off > 0; off >>= 1) v += __shfl_xor(v, off);
    return v;
}
__device__ __forceinline__ float waveReduceMax(float v) {
    for (int off = 32; off > 0; off >>= 1) v = fmaxf(v, __shfl_xor(v, off));
    return v;
}
// async global->LDS 16B copy; lds ptr must be wave-uniform-base + lane*16
typedef __attribute__((address_space(1))) const unsigned int glb_cu;
typedef __attribute__((address_space(3))) unsigned int lds_u;
__device__ __forceinline__ void async_copy16(const unsigned short* g, unsigned short* l) {
    __builtin_amdgcn_global_load_lds((glb_cu*)g, (lds_u*)l, 16, 0, 0);
}

// ---------- K1: per-channel mean of y ----------
__global__ __launch_bounds__(256) void mu_kernel(const float* __restrict__ y,
                                                 float* __restrict__ mu) {
    int c = blockIdx.x;
    int tid = threadIdx.x;
    float s = 0.f;
    const float* base = y + (size_t)c * HW;
    for (int n = 0; n < NB; n++) {
        const float* bn = base + (size_t)n * C * HW;
        for (int i = tid; i < HW; i += 256) s += bn[i];
    }
    s = waveReduceSum(s);
    __shared__ float red[4];
    int lane = tid & 63, wave = tid >> 6;
    if (lane == 0) red[wave] = s;
    __syncthreads();
    if (tid == 0) mu[c] = (red[0] + red[1] + red[2] + red[3]) * (1.0f / 16384.0f);
}

// ---------- K2: center, L2-normalize over C, transpose to (n,p,c) bf16 ----------
#define TP 32
#define TSTRIDE 257
__global__ __launch_bounds__(256) void prep_kernel(const float* __restrict__ x,
                                                   const float* __restrict__ y,
                                                   const float* __restrict__ mu,
                                                   unsigned short* __restrict__ Xn,
                                                   unsigned short* __restrict__ Yn) {
    __shared__ float smu[C];
    __shared__ float tile[TP * TSTRIDE];
    __shared__ float red[8 * 32];
    __shared__ float invn[TP];
    int tid = threadIdx.x;
    smu[tid] = mu[tid];
    int blk = blockIdx.x;
    int n = blk >> 7;                // 128 blocks per batch
    int p0 = (blk & 127) * TP;
    int tp = tid & 31, cc = tid >> 5;
    __syncthreads();
    for (int pass = 0; pass < 2; pass++) {
        const float* in = pass ? y : x;
        unsigned short* out = pass ? Yn : Xn;
        const float* base = in + (size_t)n * C * HW + p0 + tp;
        float ssq = 0.f;
        for (int c = cc; c < C; c += 8) {
            float v = base[(size_t)c * HW] - smu[c];
            tile[tp * TSTRIDE + c] = v;
            ssq += v * v;
        }
        red[cc * 32 + tp] = ssq;
        __syncthreads();
        if (tid < 32) {
            float s = 0.f;
            for (int k = 0; k < 8; k++) s += red[k * 32 + tid];
            invn[tid] = rsqrtf(s);
        }
        __syncthreads();
        int c2 = (tid & 127) * 2;
        int pp = tid >> 7;
        for (int p = pp; p < TP; p += 2) {
            float inv = invn[p];
            unsigned short b0 = f2bf(tile[p * TSTRIDE + c2] * inv);
            unsigned short b1 = f2bf(tile[p * TSTRIDE + c2 + 1] * inv);
            unsigned int pack = (unsigned int)b0 | ((unsigned int)b1 << 16);
            ((unsigned int*)out)[(size_t)(n * HW + p0 + p) * (C / 2) + (c2 >> 1)] = pack;
        }
        __syncthreads();
    }
}

// ---------- K3: batched GEMM cos = Xn * Yn^T, bf16 out ----------
#define EPSTRIDE 136
__global__ __launch_bounds__(256, 2) void gemm_cos(const unsigned short* __restrict__ Xn,
                                                   const unsigned short* __restrict__ Yn,
                                                   unsigned short* __restrict__ Cos) {
    __shared__ unsigned short lds_us[32768];   // 64 KB: A[16K ushorts] B[16K]
    int n = blockIdx.z;
    int pBase = blockIdx.y * 128, qBase = blockIdx.x * 128;
    const unsigned short* Ab = Xn + ((size_t)n * HW + pBase) * C;
    const unsigned short* Bb = Yn + ((size_t)n * HW + qBase) * C;
    int tid = threadIdx.x, lane = tid & 63, wave = tid >> 6;
    int wm = (wave >> 1) * 64, wn = (wave & 1) * 64;
    int mrow = lane & 15, quad = lane >> 4;

    f32x4 acc[4][4];
#pragma unroll
    for (int i = 0; i < 4; i++)
#pragma unroll
        for (int j = 0; j < 4; j++) acc[i][j] = (f32x4){0.f, 0.f, 0.f, 0.f};

#pragma unroll
    for (int h = 0; h < 2; h++) {
#pragma unroll
        for (int mat = 0; mat < 2; mat++) {
            const unsigned short* g = mat ? Bb : Ab;
            unsigned short* lbase = lds_us + mat * 16384;
#pragma unroll
            for (int t = 0; t < 8; t++) {
                int slot = t * 256 + tid;           // 0..2047
                int r = slot >> 4, cl = slot & 15;
                int c = h * 16 + (cl ^ (r & 15));   // global 16B-chunk index
                async_copy16(g + (size_t)r * C + c * 8, lbase + slot * 8);
            }
        }
        __syncthreads();
#pragma unroll
        for (int kkl = 0; kkl < 4; kkl++) {
            int cl4 = kkl * 4 + quad;
            int clp = cl4 ^ mrow;
            bf16x8 af[4], bfr[4];
#pragma unroll
            for (int i = 0; i < 4; i++) {
                af[i]  = *(const bf16x8*)(lds_us + (wm + i * 16 + mrow) * 128 + clp * 8);
                bfr[i] = *(const bf16x8*)(lds_us + 16384 + (wn + i * 16 + mrow) * 128 + clp * 8);
            }
#pragma unroll
            for (int i = 0; i < 4; i++)
#pragma unroll
                for (int j = 0; j < 4; j++)
                    acc[i][j] = __builtin_amdgcn_mfma_f32_16x16x32_bf16(af[i], bfr[j], acc[i][j], 0, 0, 0);
        }
        __syncthreads();
    }

    // ---- epilogue: transpose through LDS (bf16), coalesced dwordx4 stores ----
    unsigned short* epb = lds_us;  // 128 x EPSTRIDE bf16 = 34 KB
    int col = lane & 15, quad4 = quad * 4;
#pragma unroll
    for (int i = 0; i < 4; i++)
#pragma unroll
        for (int j = 0; j < 4; j++)
#pragma unroll
            for (int r = 0; r < 4; r++)
                epb[(wm + i * 16 + quad4 + r) * EPSTRIDE + wn + j * 16 + col] = f2bf(acc[i][j][r]);
    __syncthreads();
    unsigned short* Crow = Cos + (size_t)n * HW * HW;
#pragma unroll
    for (int it = 0; it < 8; it++) {
        int e = it * 2048 + tid * 8;
        int r = e >> 7, cg = e & 127;
        uint4 o = *(const uint4*)(epb + r * EPSTRIDE + cg);
        *(uint4*)(Crow + (size_t)(pBase + r) * HW + qBase + cg) = o;
    }
}

// ---------- K4: fused row stats + column logit-max, streaming, low-VGPR ----------
// Block owns 16 rows (grid 256 x NB = 1024 blocks = 4/CU). 4 rows per group;
// only the packed uint4 data (32 VGPR) + cmax[16] stay live across phases —
// unpack is rematerialized per phase. 2 barriers/group. Plain coalesced
// stores of per-chunk column maxes (NO atomics — R3 lesson).
__global__ __launch_bounds__(256, 4) void rowcol(const unsigned short* __restrict__ Cos,
                                                 float* __restrict__ partial) {
    int n = blockIdx.y, chunk = blockIdx.x;   // 0..255, 16 rows each
    int tid = threadIdx.x, lane = tid & 63, wave = tid >> 6;
    const unsigned short* rowbase = Cos + ((size_t)n * HW + chunk * 16) * HW;
    __shared__ float redm[4][4];
    __shared__ float sval[4][4];
    float cmax[16];
#pragma unroll
    for (int k = 0; k < 16; k++) cmax[k] = -1e30f;

#pragma unroll
    for (int g = 0; g < 4; g++) {
        uint4 d[4][2];
#pragma unroll
        for (int r = 0; r < 4; r++) {
            const unsigned short* rp = rowbase + (size_t)(g * 4 + r) * HW;
            d[r][0] = *(const uint4*)(rp + tid * 8);
            d[r][1] = *(const uint4*)(rp + 2048 + tid * 8);
        }
        // phase 1: row maxes (unpack, reduce, drop)
#pragma unroll
        for (int r = 0; r < 4; r++) {
            float v[16];
            unpack8(d[r][0], v); unpack8(d[r][1], v + 8);
            float m = v[0];
#pragma unroll
            for (int k = 1; k < 16; k++) m = fmaxf(m, v[k]);
            m = waveReduceMax(m);
            if (lane == 0) redm[r][wave] = m;
        }
        __syncthreads();
        float alpha[4], basec[4];
#pragma unroll
        for (int r = 0; r < 4; r++) {
            float M = fmaxf(fmaxf(redm[r][0], redm[r][1]), fmaxf(redm[r][2], redm[r][3]));
            alpha[r] = 2.0f / ((1.0f - M) + EPSF);
            basec[r] = 2.0f - alpha[r];
        }
        // phase 2: exp row-sums (re-unpack)
#pragma unroll
        for (int r = 0; r < 4; r++) {
            float v[16];
            unpack8(d[r][0], v); unpack8(d[r][1], v + 8);
            float s = 0.f;
#pragma unroll
            for (int k = 0; k < 16; k++) s += __expf(fmaf(alpha[r], v[r == r ? k : k], basec[r]));
            s = waveReduceSum(s);
            if (lane == 0) sval[r][wave] = s;
        }
        __syncthreads();
        // phase 3: beta + column logit-max (re-unpack)
#pragma unroll
        for (int r = 0; r < 4; r++) {
            float S = sval[r][0] + sval[r][1] + sval[r][2] + sval[r][3];
            float beta = basec[r] - __logf(S);
            float v[16];
            unpack8(d[r][0], v); unpack8(d[r][1], v + 8);
#pragma unroll
            for (int k = 0; k < 16; k++) cmax[k] = fmaxf(cmax[k], fmaf(alpha[r], v[k], beta));
        }
        // barrier safety: redm next written post-bar2 (phase1 g+1); sval next
        // written post-bar1(g+1); all prior reads complete by then.
    }
    float* outp = partial + ((size_t)(n * 256 + chunk)) * HW;
#pragma unroll
    for (int k = 0; k < 8; k += 4) {
        float4 o0 = {cmax[k], cmax[k + 1], cmax[k + 2], cmax[k + 3]};
        *(float4*)(outp + tid * 8 + k) = o0;
        float4 o1 = {cmax[k + 8], cmax[k + 9], cmax[k + 10], cmax[k + 11]};
        *(float4*)(outp + 2048 + tid * 8 + k) = o1;
    }
}

// ---------- K5a: reduce column partials over 16-chunk groups ----------
__global__ __launch_bounds__(256) void colmax1(const float* __restrict__ partial,
                                               float* __restrict__ partial2) {
    int n = blockIdx.z, grp = blockIdx.y;
    int q = blockIdx.x * 256 + threadIdx.x;
    const float* p = partial + ((size_t)n * 256 + grp * 16) * HW + q;
    float m = -1e30f;
#pragma unroll
    for (int c = 0; c < 16; c++) m = fmaxf(m, p[(size_t)c * HW]);
    partial2[((size_t)n * 16 + grp) * HW + q] = m;
}

// ---------- K5b: final column max, exp, sum over q (one block per batch) ----------
__global__ __launch_bounds__(1024) void colfinal(const float* __restrict__ partial2,
                                                 float* __restrict__ cxsum) {
    int n = blockIdx.x;
    int tid = threadIdx.x;
    float s = 0.f;
    for (int q = tid; q < HW; q += 1024) {
        const float* p = partial2 + (size_t)n * 16 * HW + q;
        float m = -1e30f;
#pragma unroll
        for (int g = 0; g < 16; g++) m = fmaxf(m, p[(size_t)g * HW]);
        s += __expf(m);
    }
    s = waveReduceSum(s);
    __shared__ float red[16];
    int lane = tid & 63, wave = tid >> 6;
    if (lane == 0) red[wave] = s;
    __syncthreads();
    if (tid == 0) {
        float S = 0.f;
        for (int w = 0; w < 16; w++) S += red[w];
        cxsum[n] = S;
    }
}

// ---------- K6: final loss ----------
__global__ void finalize(const float* __restrict__ cxsum, float* __restrict__ out) {
    if (threadIdx.x == 0 && blockIdx.x == 0) {
        float loss = 0.f;
        for (int n = 0; n < NB; n++) {
            float cx = cxsum[n] * (1.0f / 4096.0f);
            loss += -logf(cx + EPSF);
        }
        out[0] = loss * 0.25f;
    }
}

// ---------- launch ----------
extern "C" void kernel_launch(void* const* d_in, const int* in_sizes, int n_in,
                              void* d_out, int out_size, void* d_ws, size_t ws_size,
                              hipStream_t stream) {
    const float* x = (const float*)d_in[0];
    const float* y = (const float*)d_in[1];
    float* out = (float*)d_out;
    char* ws = (char*)d_ws;

    float* mu            = (float*)(ws + 0);                   // 1 KiB
    float* cxsum         = (float*)(ws + 1024);                // 16 B
    float* partial2      = (float*)(ws + 4096);                // 1 MiB
    unsigned short* Xn   = (unsigned short*)(ws + 2097152);    // 8 MiB
    unsigned short* Yn   = (unsigned short*)(ws + 10485760);   // 8 MiB
    float* partial       = (float*)(ws + 2097152);             // 16.7 MiB (aliases Xn/Yn, used after gemm)
    unsigned short* Cos  = (unsigned short*)(ws + 20971520);   // 128 MiB

    mu_kernel<<<C, 256, 0, stream>>>(y, mu);
    prep_kernel<<<NROWS / TP, 256, 0, stream>>>(x, y, mu, Xn, Yn);
    gemm_cos<<<dim3(HW / 128, HW / 128, NB), 256, 0, stream>>>(Xn, Yn, Cos);
    rowcol<<<dim3(256, NB), 256, 0, stream>>>(Cos, partial);
    colmax1<<<dim3(16, 16, NB), 256, 0, stream>>>(partial, partial2);
    colfinal<<<NB, 1024, 0, stream>>>(partial2, cxsum);
    finalize<<<1, 64, 0, stream>>>(cxsum, out);
}

// Round 5
// 282.851 us; speedup vs baseline: 1.3265x; 1.3265x over previous
//
#include <hip/hip_runtime.h>
#include <hip/hip_bf16.h>

// ---------- types ----------
typedef short bf16x8 __attribute__((ext_vector_type(8)));
typedef float f32x4 __attribute__((ext_vector_type(4)));

#define NB 4
#define C 256
#define HW 4096
#define NROWS (NB * HW)   // 16384
#define EPSF 1e-5f

// ---------- helpers ----------
__device__ __forceinline__ unsigned short f2bf(float f) {
    unsigned int u = __float_as_uint(f);
    unsigned int r = u + 0x7fffu + ((u >> 16) & 1u);
    return (unsigned short)(r >> 16);
}
__device__ __forceinline__ float bf2f(unsigned int h) {
    return __uint_as_float(h << 16);
}
__device__ __forceinline__ void unpack8(uint4 u, float* v) {
    unsigned int w0 = u.x, w1 = u.y, w2 = u.z, w3 = u.w;
    v[0] = bf2f(w0 & 0xffffu); v[1] = bf2f(w0 >> 16);
    v[2] = bf2f(w1 & 0xffffu); v[3] = bf2f(w1 >> 16);
    v[4] = bf2f(w2 & 0xffffu); v[5] = bf2f(w2 >> 16);
    v[6] = bf2f(w3 & 0xffffu); v[7] = bf2f(w3 >> 16);
}
__device__ __forceinline__ float waveReduceSum(float v) {
    for (int off = 32; off > 0; off >>= 1) v += __shfl_xor(v, off);
    return v;
}
// async global->LDS 16B copy; lds ptr must be wave-uniform-base + lane*16
typedef __attribute__((address_space(1))) const unsigned int glb_cu;
typedef __attribute__((address_space(3))) unsigned int lds_u;
__device__ __forceinline__ void async_copy16(const unsigned short* g, unsigned short* l) {
    __builtin_amdgcn_global_load_lds((glb_cu*)g, (lds_u*)l, 16, 0, 0);
}

// ---------- K1: per-channel mean of y ----------
__global__ __launch_bounds__(256) void mu_kernel(const float* __restrict__ y,
                                                 float* __restrict__ mu) {
    int c = blockIdx.x;
    int tid = threadIdx.x;
    float s = 0.f;
    const float* base = y + (size_t)c * HW;
    for (int n = 0; n < NB; n++) {
        const float* bn = base + (size_t)n * C * HW;
        for (int i = tid; i < HW; i += 256) s += bn[i];
    }
    s = waveReduceSum(s);
    __shared__ float red[4];
    int lane = tid & 63, wave = tid >> 6;
    if (lane == 0) red[wave] = s;
    __syncthreads();
    if (tid == 0) mu[c] = (red[0] + red[1] + red[2] + red[3]) * (1.0f / 16384.0f);
}

// ---------- K2: center, L2-normalize over C, transpose to (n,p,c) bf16 ----------
#define TP 32
#define TSTRIDE 257
__global__ __launch_bounds__(256) void prep_kernel(const float* __restrict__ x,
                                                   const float* __restrict__ y,
                                                   const float* __restrict__ mu,
                                                   unsigned short* __restrict__ Xn,
                                                   unsigned short* __restrict__ Yn) {
    __shared__ float smu[C];
    __shared__ float tile[TP * TSTRIDE];
    __shared__ float red[8 * 32];
    __shared__ float invn[TP];
    int tid = threadIdx.x;
    smu[tid] = mu[tid];
    int blk = blockIdx.x;
    int n = blk >> 7;                // 128 blocks per batch
    int p0 = (blk & 127) * TP;
    int tp = tid & 31, cc = tid >> 5;
    __syncthreads();
    for (int pass = 0; pass < 2; pass++) {
        const float* in = pass ? y : x;
        unsigned short* out = pass ? Yn : Xn;
        const float* base = in + (size_t)n * C * HW + p0 + tp;
        float ssq = 0.f;
        for (int c = cc; c < C; c += 8) {
            float v = base[(size_t)c * HW] - smu[c];
            tile[tp * TSTRIDE + c] = v;
            ssq += v * v;
        }
        red[cc * 32 + tp] = ssq;
        __syncthreads();
        if (tid < 32) {
            float s = 0.f;
            for (int k = 0; k < 8; k++) s += red[k * 32 + tid];
            invn[tid] = rsqrtf(s);
        }
        __syncthreads();
        int c2 = (tid & 127) * 2;
        int pp = tid >> 7;
        for (int p = pp; p < TP; p += 2) {
            float inv = invn[p];
            unsigned short b0 = f2bf(tile[p * TSTRIDE + c2] * inv);
            unsigned short b1 = f2bf(tile[p * TSTRIDE + c2 + 1] * inv);
            unsigned int pack = (unsigned int)b0 | ((unsigned int)b1 << 16);
            ((unsigned int*)out)[(size_t)(n * HW + p0 + p) * (C / 2) + (c2 >> 1)] = pack;
        }
        __syncthreads();
    }
}

// ---------- K3: batched GEMM cos = Xn * Yn^T, bf16 out ----------
#define EPSTRIDE 136
__global__ __launch_bounds__(256, 2) void gemm_cos(const unsigned short* __restrict__ Xn,
                                                   const unsigned short* __restrict__ Yn,
                                                   unsigned short* __restrict__ Cos) {
    __shared__ unsigned short lds_us[32768];   // 64 KB: A[16K ushorts] B[16K]
    int n = blockIdx.z;
    int pBase = blockIdx.y * 128, qBase = blockIdx.x * 128;
    const unsigned short* Ab = Xn + ((size_t)n * HW + pBase) * C;
    const unsigned short* Bb = Yn + ((size_t)n * HW + qBase) * C;
    int tid = threadIdx.x, lane = tid & 63, wave = tid >> 6;
    int wm = (wave >> 1) * 64, wn = (wave & 1) * 64;
    int mrow = lane & 15, quad = lane >> 4;

    f32x4 acc[4][4];
#pragma unroll
    for (int i = 0; i < 4; i++)
#pragma unroll
        for (int j = 0; j < 4; j++) acc[i][j] = (f32x4){0.f, 0.f, 0.f, 0.f};

#pragma unroll
    for (int h = 0; h < 2; h++) {
#pragma unroll
        for (int mat = 0; mat < 2; mat++) {
            const unsigned short* g = mat ? Bb : Ab;
            unsigned short* lbase = lds_us + mat * 16384;
#pragma unroll
            for (int t = 0; t < 8; t++) {
                int slot = t * 256 + tid;           // 0..2047
                int r = slot >> 4, cl = slot & 15;
                int c = h * 16 + (cl ^ (r & 15));   // global 16B-chunk index
                async_copy16(g + (size_t)r * C + c * 8, lbase + slot * 8);
            }
        }
        __syncthreads();
#pragma unroll
        for (int kkl = 0; kkl < 4; kkl++) {
            int cl4 = kkl * 4 + quad;
            int clp = cl4 ^ mrow;
            bf16x8 af[4], bfr[4];
#pragma unroll
            for (int i = 0; i < 4; i++) {
                af[i]  = *(const bf16x8*)(lds_us + (wm + i * 16 + mrow) * 128 + clp * 8);
                bfr[i] = *(const bf16x8*)(lds_us + 16384 + (wn + i * 16 + mrow) * 128 + clp * 8);
            }
#pragma unroll
            for (int i = 0; i < 4; i++)
#pragma unroll
                for (int j = 0; j < 4; j++)
                    acc[i][j] = __builtin_amdgcn_mfma_f32_16x16x32_bf16(af[i], bfr[j], acc[i][j], 0, 0, 0);
        }
        __syncthreads();
    }

    // ---- epilogue: transpose through LDS (bf16), coalesced dwordx4 stores ----
    unsigned short* epb = lds_us;  // 128 x EPSTRIDE bf16 = 34 KB
    int col = lane & 15, quad4 = quad * 4;
#pragma unroll
    for (int i = 0; i < 4; i++)
#pragma unroll
        for (int j = 0; j < 4; j++)
#pragma unroll
            for (int r = 0; r < 4; r++)
                epb[(wm + i * 16 + quad4 + r) * EPSTRIDE + wn + j * 16 + col] = f2bf(acc[i][j][r]);
    __syncthreads();
    unsigned short* Crow = Cos + (size_t)n * HW * HW;
#pragma unroll
    for (int it = 0; it < 8; it++) {
        int e = it * 2048 + tid * 8;
        int r = e >> 7, cg = e & 127;
        uint4 o = *(const uint4*)(epb + r * EPSTRIDE + cg);
        *(uint4*)(Crow + (size_t)(pBase + r) * HW + qBase + cg) = o;
    }
}

// ---------- K4: fused row stats + column logit-max (R2 structure, 8 rows/block) ----------
// Register-resident packed data: d[8][2] = 64 VGPRs live across 3 phases.
// (256,3) cap (~170 VGPR) leaves room -> NO SPILL (R4 lesson: don't starve
// the allocator). Grid 2048 blocks. 2 barriers total. bf16 partial out.
__global__ __launch_bounds__(256, 3) void rowcol(const unsigned short* __restrict__ Cos,
                                                 unsigned short* __restrict__ partial) {
    int n = blockIdx.y, chunk = blockIdx.x;   // 0..511, 8 rows each
    int tid = threadIdx.x, lane = tid & 63, wave = tid >> 6;
    const unsigned short* rowbase = Cos + ((size_t)n * HW + chunk * 8) * HW;
    __shared__ float redm[8][4];
    __shared__ float sval[8][4];

    uint4 d[8][2];
#pragma unroll
    for (int r = 0; r < 8; r++) {
        const unsigned short* rp = rowbase + (size_t)r * HW;
        d[r][0] = *(const uint4*)(rp + tid * 8);
        d[r][1] = *(const uint4*)(rp + 2048 + tid * 8);
    }

    // phase 1: row maxes (batched butterfly)
    float m8[8];
#pragma unroll
    for (int r = 0; r < 8; r++) {
        float v[16];
        unpack8(d[r][0], v); unpack8(d[r][1], v + 8);
        float m = v[0];
#pragma unroll
        for (int k = 1; k < 16; k++) m = fmaxf(m, v[k]);
        m8[r] = m;
    }
#pragma unroll
    for (int off = 32; off > 0; off >>= 1)
#pragma unroll
        for (int r = 0; r < 8; r++) m8[r] = fmaxf(m8[r], __shfl_xor(m8[r], off));
    if (lane == 0)
#pragma unroll
        for (int r = 0; r < 8; r++) redm[r][wave] = m8[r];
    __syncthreads();

    float alpha[8], basec[8];
#pragma unroll
    for (int r = 0; r < 8; r++) {
        float M = fmaxf(fmaxf(redm[r][0], redm[r][1]), fmaxf(redm[r][2], redm[r][3]));
        alpha[r] = 2.0f / ((1.0f - M) + EPSF);
        basec[r] = 2.0f - alpha[r];
    }

    // phase 2: exp row-sums (batched butterfly)
    float s8[8];
#pragma unroll
    for (int r = 0; r < 8; r++) {
        float v[16];
        unpack8(d[r][0], v); unpack8(d[r][1], v + 8);
        float s = 0.f;
#pragma unroll
        for (int k = 0; k < 16; k++) s += __expf(fmaf(alpha[r], v[k], basec[r]));
        s8[r] = s;
    }
#pragma unroll
    for (int off = 32; off > 0; off >>= 1)
#pragma unroll
        for (int r = 0; r < 8; r++) s8[r] += __shfl_xor(s8[r], off);
    if (lane == 0)
#pragma unroll
        for (int r = 0; r < 8; r++) sval[r][wave] = s8[r];
    __syncthreads();

    // phase 3: beta + column logit-max
    float cmax[16];
#pragma unroll
    for (int k = 0; k < 16; k++) cmax[k] = -1e30f;
#pragma unroll
    for (int r = 0; r < 8; r++) {
        float S = sval[r][0] + sval[r][1] + sval[r][2] + sval[r][3];
        float beta = basec[r] - __logf(S);
        float v[16];
        unpack8(d[r][0], v); unpack8(d[r][1], v + 8);
#pragma unroll
        for (int k = 0; k < 16; k++) cmax[k] = fmaxf(cmax[k], fmaf(alpha[r], v[k], beta));
    }

    // store as bf16, packed uint4 (q = tid*8+k and 2048+tid*8+k)
    unsigned short* outp = partial + ((size_t)(n * 512 + chunk)) * HW;
    uint4 o0, o1;
    o0.x = (unsigned int)f2bf(cmax[0]) | ((unsigned int)f2bf(cmax[1]) << 16);
    o0.y = (unsigned int)f2bf(cmax[2]) | ((unsigned int)f2bf(cmax[3]) << 16);
    o0.z = (unsigned int)f2bf(cmax[4]) | ((unsigned int)f2bf(cmax[5]) << 16);
    o0.w = (unsigned int)f2bf(cmax[6]) | ((unsigned int)f2bf(cmax[7]) << 16);
    o1.x = (unsigned int)f2bf(cmax[8]) | ((unsigned int)f2bf(cmax[9]) << 16);
    o1.y = (unsigned int)f2bf(cmax[10]) | ((unsigned int)f2bf(cmax[11]) << 16);
    o1.z = (unsigned int)f2bf(cmax[12]) | ((unsigned int)f2bf(cmax[13]) << 16);
    o1.w = (unsigned int)f2bf(cmax[14]) | ((unsigned int)f2bf(cmax[15]) << 16);
    *(uint4*)(outp + tid * 8) = o0;
    *(uint4*)(outp + 2048 + tid * 8) = o1;
}

// ---------- K5: column max over 512 chunks, exp, sum over q ----------
__global__ __launch_bounds__(256) void colfinal(const unsigned short* __restrict__ partial,
                                                float* __restrict__ cxsum) {
    int n = blockIdx.y;
    int q = blockIdx.x * 256 + threadIdx.x;
    const unsigned short* p = partial + (size_t)n * 512 * HW + q;
    float m = -1e30f;
#pragma unroll 8
    for (int c = 0; c < 512; c++) m = fmaxf(m, bf2f(p[(size_t)c * HW]));
    float val = __expf(m);
    val = waveReduceSum(val);
    __shared__ float red[4];
    int lane = threadIdx.x & 63, wave = threadIdx.x >> 6;
    if (lane == 0) red[wave] = val;
    __syncthreads();
    if (threadIdx.x == 0)
        atomicAdd(&cxsum[n], red[0] + red[1] + red[2] + red[3]);
}

// ---------- K6: final loss ----------
__global__ void finalize(const float* __restrict__ cxsum, float* __restrict__ out) {
    if (threadIdx.x == 0 && blockIdx.x == 0) {
        float loss = 0.f;
        for (int n = 0; n < NB; n++) {
            float cx = cxsum[n] * (1.0f / 4096.0f);
            loss += -logf(cx + EPSF);
        }
        out[0] = loss * 0.25f;
    }
}

// ---------- launch ----------
extern "C" void kernel_launch(void* const* d_in, const int* in_sizes, int n_in,
                              void* d_out, int out_size, void* d_ws, size_t ws_size,
                              hipStream_t stream) {
    const float* x = (const float*)d_in[0];
    const float* y = (const float*)d_in[1];
    float* out = (float*)d_out;
    char* ws = (char*)d_ws;

    float* mu               = (float*)(ws + 0);                   // 1 KiB
    float* cxsum            = (float*)(ws + 1024);                // 16 B
    unsigned short* Xn      = (unsigned short*)(ws + 2097152);    // 8 MiB
    unsigned short* Yn      = (unsigned short*)(ws + 10485760);   // 8 MiB
    unsigned short* partial = (unsigned short*)(ws + 2097152);    // 16 MiB bf16 (aliases Xn+Yn, used after gemm)
    unsigned short* Cos     = (unsigned short*)(ws + 18874368);   // 128 MiB

    hipMemsetAsync(cxsum, 0, NB * sizeof(float), stream);

    mu_kernel<<<C, 256, 0, stream>>>(y, mu);
    prep_kernel<<<NROWS / TP, 256, 0, stream>>>(x, y, mu, Xn, Yn);
    gemm_cos<<<dim3(HW / 128, HW / 128, NB), 256, 0, stream>>>(Xn, Yn, Cos);
    rowcol<<<dim3(512, NB), 256, 0, stream>>>(Cos, partial);
    colfinal<<<dim3(16, NB), 256, 0, stream>>>(partial, cxsum);
    finalize<<<1, 64, 0, stream>>>(cxsum, out);
}

// Round 6
// 199.271 us; speedup vs baseline: 1.8828x; 1.4194x over previous
//
#include <hip/hip_runtime.h>
#include <hip/hip_bf16.h>

// ---------- types ----------
typedef short bf16x8 __attribute__((ext_vector_type(8)));
typedef float f32x4 __attribute__((ext_vector_type(4)));

#define NB 4
#define C 256
#define HW 4096
#define NROWS (NB * HW)   // 16384
#define EPSF 1e-5f

// ---------- helpers ----------
__device__ __forceinline__ unsigned short f2bf(float f) {
    unsigned int u = __float_as_uint(f);
    unsigned int r = u + 0x7fffu + ((u >> 16) & 1u);
    return (unsigned short)(r >> 16);
}
__device__ __forceinline__ float bf2f(unsigned int h) {
    return __uint_as_float(h << 16);
}
__device__ __forceinline__ void unpack8(uint4 u, float* v) {
    unsigned int w0 = u.x, w1 = u.y, w2 = u.z, w3 = u.w;
    v[0] = bf2f(w0 & 0xffffu); v[1] = bf2f(w0 >> 16);
    v[2] = bf2f(w1 & 0xffffu); v[3] = bf2f(w1 >> 16);
    v[4] = bf2f(w2 & 0xffffu); v[5] = bf2f(w2 >> 16);
    v[6] = bf2f(w3 & 0xffffu); v[7] = bf2f(w3 >> 16);
}
__device__ __forceinline__ float waveReduceSum(float v) {
    for (int off = 32; off > 0; off >>= 1) v += __shfl_xor(v, off);
    return v;
}
// async global->LDS 16B copy; lds ptr must be wave-uniform-base + lane*16
typedef __attribute__((address_space(1))) const unsigned int glb_cu;
typedef __attribute__((address_space(3))) unsigned int lds_u;
__device__ __forceinline__ void async_copy16(const unsigned short* g, unsigned short* l) {
    __builtin_amdgcn_global_load_lds((glb_cu*)g, (lds_u*)l, 16, 0, 0);
}

// ---------- K1: per-channel mean of y ----------
__global__ __launch_bounds__(256) void mu_kernel(const float* __restrict__ y,
                                                 float* __restrict__ mu) {
    int c = blockIdx.x;
    int tid = threadIdx.x;
    float s = 0.f;
    const float* base = y + (size_t)c * HW;
    for (int n = 0; n < NB; n++) {
        const float* bn = base + (size_t)n * C * HW;
        for (int i = tid; i < HW; i += 256) s += bn[i];
    }
    s = waveReduceSum(s);
    __shared__ float red[4];
    int lane = tid & 63, wave = tid >> 6;
    if (lane == 0) red[wave] = s;
    __syncthreads();
    if (tid == 0) mu[c] = (red[0] + red[1] + red[2] + red[3]) * (1.0f / 16384.0f);
}

// ---------- K2: center, L2-normalize over C, transpose to (n,p,c) bf16 ----------
#define TP 32
#define TSTRIDE 257
__global__ __launch_bounds__(256) void prep_kernel(const float* __restrict__ x,
                                                   const float* __restrict__ y,
                                                   const float* __restrict__ mu,
                                                   unsigned short* __restrict__ Xn,
                                                   unsigned short* __restrict__ Yn) {
    __shared__ float smu[C];
    __shared__ float tile[TP * TSTRIDE];
    __shared__ float red[8 * 32];
    __shared__ float invn[TP];
    int tid = threadIdx.x;
    smu[tid] = mu[tid];
    int blk = blockIdx.x;
    int n = blk >> 7;                // 128 blocks per batch
    int p0 = (blk & 127) * TP;
    int tp = tid & 31, cc = tid >> 5;
    __syncthreads();
    for (int pass = 0; pass < 2; pass++) {
        const float* in = pass ? y : x;
        unsigned short* out = pass ? Yn : Xn;
        const float* base = in + (size_t)n * C * HW + p0 + tp;
        float ssq = 0.f;
        for (int c = cc; c < C; c += 8) {
            float v = base[(size_t)c * HW] - smu[c];
            tile[tp * TSTRIDE + c] = v;
            ssq += v * v;
        }
        red[cc * 32 + tp] = ssq;
        __syncthreads();
        if (tid < 32) {
            float s = 0.f;
            for (int k = 0; k < 8; k++) s += red[k * 32 + tid];
            invn[tid] = rsqrtf(s);
        }
        __syncthreads();
        int c2 = (tid & 127) * 2;
        int pp = tid >> 7;
        for (int p = pp; p < TP; p += 2) {
            float inv = invn[p];
            unsigned short b0 = f2bf(tile[p * TSTRIDE + c2] * inv);
            unsigned short b1 = f2bf(tile[p * TSTRIDE + c2 + 1] * inv);
            unsigned int pack = (unsigned int)b0 | ((unsigned int)b1 << 16);
            ((unsigned int*)out)[(size_t)(n * HW + p0 + p) * (C / 2) + (c2 >> 1)] = pack;
        }
        __syncthreads();
    }
}

// ---------- K3: batched GEMM cos = Xn * Yn^T, bf16 out ----------
#define EPSTRIDE 136
__global__ __launch_bounds__(256, 2) void gemm_cos(const unsigned short* __restrict__ Xn,
                                                   const unsigned short* __restrict__ Yn,
                                                   unsigned short* __restrict__ Cos) {
    __shared__ unsigned short lds_us[32768];   // 64 KB: A[16K ushorts] B[16K]
    int n = blockIdx.z;
    int pBase = blockIdx.y * 128, qBase = blockIdx.x * 128;
    const unsigned short* Ab = Xn + ((size_t)n * HW + pBase) * C;
    const unsigned short* Bb = Yn + ((size_t)n * HW + qBase) * C;
    int tid = threadIdx.x, lane = tid & 63, wave = tid >> 6;
    int wm = (wave >> 1) * 64, wn = (wave & 1) * 64;
    int mrow = lane & 15, quad = lane >> 4;

    f32x4 acc[4][4];
#pragma unroll
    for (int i = 0; i < 4; i++)
#pragma unroll
        for (int j = 0; j < 4; j++) acc[i][j] = (f32x4){0.f, 0.f, 0.f, 0.f};

#pragma unroll
    for (int h = 0; h < 2; h++) {
#pragma unroll
        for (int mat = 0; mat < 2; mat++) {
            const unsigned short* g = mat ? Bb : Ab;
            unsigned short* lbase = lds_us + mat * 16384;
#pragma unroll
            for (int t = 0; t < 8; t++) {
                int slot = t * 256 + tid;           // 0..2047
                int r = slot >> 4, cl = slot & 15;
                int c = h * 16 + (cl ^ (r & 15));   // global 16B-chunk index
                async_copy16(g + (size_t)r * C + c * 8, lbase + slot * 8);
            }
        }
        __syncthreads();
#pragma unroll
        for (int kkl = 0; kkl < 4; kkl++) {
            int cl4 = kkl * 4 + quad;
            int clp = cl4 ^ mrow;
            bf16x8 af[4], bfr[4];
#pragma unroll
            for (int i = 0; i < 4; i++) {
                af[i]  = *(const bf16x8*)(lds_us + (wm + i * 16 + mrow) * 128 + clp * 8);
                bfr[i] = *(const bf16x8*)(lds_us + 16384 + (wn + i * 16 + mrow) * 128 + clp * 8);
            }
#pragma unroll
            for (int i = 0; i < 4; i++)
#pragma unroll
                for (int j = 0; j < 4; j++)
                    acc[i][j] = __builtin_amdgcn_mfma_f32_16x16x32_bf16(af[i], bfr[j], acc[i][j], 0, 0, 0);
        }
        __syncthreads();
    }

    // ---- epilogue: transpose through LDS (bf16), coalesced dwordx4 stores ----
    unsigned short* epb = lds_us;  // 128 x EPSTRIDE bf16 = 34 KB
    int col = lane & 15, quad4 = quad * 4;
#pragma unroll
    for (int i = 0; i < 4; i++)
#pragma unroll
        for (int j = 0; j < 4; j++)
#pragma unroll
            for (int r = 0; r < 4; r++)
                epb[(wm + i * 16 + quad4 + r) * EPSTRIDE + wn + j * 16 + col] = f2bf(acc[i][j][r]);
    __syncthreads();
    unsigned short* Crow = Cos + (size_t)n * HW * HW;
#pragma unroll
    for (int it = 0; it < 8; it++) {
        int e = it * 2048 + tid * 8;
        int r = e >> 7, cg = e & 127;
        uint4 o = *(const uint4*)(epb + r * EPSTRIDE + cg);
        *(uint4*)(Crow + (size_t)(pBase + r) * HW + qBase + cg) = o;
    }
}

// ---------- K4: fused row stats + column logit-max (8 rows/block, reg-resident) ----------
__global__ __launch_bounds__(256, 3) void rowcol(const unsigned short* __restrict__ Cos,
                                                 unsigned short* __restrict__ partial) {
    int n = blockIdx.y, chunk = blockIdx.x;   // 0..511, 8 rows each
    int tid = threadIdx.x, lane = tid & 63, wave = tid >> 6;
    const unsigned short* rowbase = Cos + ((size_t)n * HW + chunk * 8) * HW;
    __shared__ float redm[8][4];
    __shared__ float sval[8][4];

    uint4 d[8][2];
#pragma unroll
    for (int r = 0; r < 8; r++) {
        const unsigned short* rp = rowbase + (size_t)r * HW;
        d[r][0] = *(const uint4*)(rp + tid * 8);
        d[r][1] = *(const uint4*)(rp + 2048 + tid * 8);
    }

    // phase 1: row maxes (batched butterfly)
    float m8[8];
#pragma unroll
    for (int r = 0; r < 8; r++) {
        float v[16];
        unpack8(d[r][0], v); unpack8(d[r][1], v + 8);
        float m = v[0];
#pragma unroll
        for (int k = 1; k < 16; k++) m = fmaxf(m, v[k]);
        m8[r] = m;
    }
#pragma unroll
    for (int off = 32; off > 0; off >>= 1)
#pragma unroll
        for (int r = 0; r < 8; r++) m8[r] = fmaxf(m8[r], __shfl_xor(m8[r], off));
    if (lane == 0)
#pragma unroll
        for (int r = 0; r < 8; r++) redm[r][wave] = m8[r];
    __syncthreads();

    float alpha[8], basec[8];
#pragma unroll
    for (int r = 0; r < 8; r++) {
        float M = fmaxf(fmaxf(redm[r][0], redm[r][1]), fmaxf(redm[r][2], redm[r][3]));
        alpha[r] = 2.0f / ((1.0f - M) + EPSF);
        basec[r] = 2.0f - alpha[r];
    }

    // phase 2: exp row-sums (batched butterfly)
    float s8[8];
#pragma unroll
    for (int r = 0; r < 8; r++) {
        float v[16];
        unpack8(d[r][0], v); unpack8(d[r][1], v + 8);
        float s = 0.f;
#pragma unroll
        for (int k = 0; k < 16; k++) s += __expf(fmaf(alpha[r], v[k], basec[r]));
        s8[r] = s;
    }
#pragma unroll
    for (int off = 32; off > 0; off >>= 1)
#pragma unroll
        for (int r = 0; r < 8; r++) s8[r] += __shfl_xor(s8[r], off);
    if (lane == 0)
#pragma unroll
        for (int r = 0; r < 8; r++) sval[r][wave] = s8[r];
    __syncthreads();

    // phase 3: beta + column logit-max
    float cmax[16];
#pragma unroll
    for (int k = 0; k < 16; k++) cmax[k] = -1e30f;
#pragma unroll
    for (int r = 0; r < 8; r++) {
        float S = sval[r][0] + sval[r][1] + sval[r][2] + sval[r][3];
        float beta = basec[r] - __logf(S);
        float v[16];
        unpack8(d[r][0], v); unpack8(d[r][1], v + 8);
#pragma unroll
        for (int k = 0; k < 16; k++) cmax[k] = fmaxf(cmax[k], fmaf(alpha[r], v[k], beta));
    }

    // store as bf16, packed uint4 (q = tid*8+k and 2048+tid*8+k)
    unsigned short* outp = partial + ((size_t)(n * 512 + chunk)) * HW;
    uint4 o0, o1;
    o0.x = (unsigned int)f2bf(cmax[0]) | ((unsigned int)f2bf(cmax[1]) << 16);
    o0.y = (unsigned int)f2bf(cmax[2]) | ((unsigned int)f2bf(cmax[3]) << 16);
    o0.z = (unsigned int)f2bf(cmax[4]) | ((unsigned int)f2bf(cmax[5]) << 16);
    o0.w = (unsigned int)f2bf(cmax[6]) | ((unsigned int)f2bf(cmax[7]) << 16);
    o1.x = (unsigned int)f2bf(cmax[8]) | ((unsigned int)f2bf(cmax[9]) << 16);
    o1.y = (unsigned int)f2bf(cmax[10]) | ((unsigned int)f2bf(cmax[11]) << 16);
    o1.z = (unsigned int)f2bf(cmax[12]) | ((unsigned int)f2bf(cmax[13]) << 16);
    o1.w = (unsigned int)f2bf(cmax[14]) | ((unsigned int)f2bf(cmax[15]) << 16);
    *(uint4*)(outp + tid * 8) = o0;
    *(uint4*)(outp + 2048 + tid * 8) = o1;
}

// ---------- K5a: column max over 32-chunk groups (coalesced uint4 reads) ----------
__global__ __launch_bounds__(256) void colmax1(const unsigned short* __restrict__ partial,
                                               float* __restrict__ partial2) {
    int n = blockIdx.z, cg = blockIdx.y;        // 16 chunk-groups of 32
    int q0 = blockIdx.x * 2048 + threadIdx.x * 8;  // 2 q-tiles
    const unsigned short* p = partial + ((size_t)(n * 512 + cg * 32)) * HW + q0;
    float mx[8];
#pragma unroll
    for (int k = 0; k < 8; k++) mx[k] = -1e30f;
    for (int c = 0; c < 32; c++) {
        uint4 u = *(const uint4*)(p + (size_t)c * HW);
        float v[8];
        unpack8(u, v);
#pragma unroll
        for (int k = 0; k < 8; k++) mx[k] = fmaxf(mx[k], v[k]);
    }
    float* o = partial2 + ((size_t)(n * 16 + cg)) * HW + q0;
#pragma unroll
    for (int k = 0; k < 8; k += 4) {
        float4 ov = {mx[k], mx[k + 1], mx[k + 2], mx[k + 3]};
        *(float4*)(o + k) = ov;
    }
}

// ---------- K5b: final column max over 16 groups, exp, sum over q ----------
__global__ __launch_bounds__(1024) void colfinal2(const float* __restrict__ partial2,
                                                  float* __restrict__ cxsum) {
    int n = blockIdx.x;
    int tid = threadIdx.x;
    const float* p = partial2 + (size_t)n * 16 * HW + tid * 4;
    float4 m = {-1e30f, -1e30f, -1e30f, -1e30f};
#pragma unroll
    for (int g = 0; g < 16; g++) {
        float4 v = *(const float4*)(p + (size_t)g * HW);
        m.x = fmaxf(m.x, v.x); m.y = fmaxf(m.y, v.y);
        m.z = fmaxf(m.z, v.z); m.w = fmaxf(m.w, v.w);
    }
    float s = __expf(m.x) + __expf(m.y) + __expf(m.z) + __expf(m.w);
    s = waveReduceSum(s);
    __shared__ float red[16];
    int lane = tid & 63, wave = tid >> 6;
    if (lane == 0) red[wave] = s;
    __syncthreads();
    if (tid == 0) {
        float S = 0.f;
        for (int w = 0; w < 16; w++) S += red[w];
        cxsum[n] = S;
    }
}

// ---------- K6: final loss ----------
__global__ void finalize(const float* __restrict__ cxsum, float* __restrict__ out) {
    if (threadIdx.x == 0 && blockIdx.x == 0) {
        float loss = 0.f;
        for (int n = 0; n < NB; n++) {
            float cx = cxsum[n] * (1.0f / 4096.0f);
            loss += -logf(cx + EPSF);
        }
        out[0] = loss * 0.25f;
    }
}

// ---------- launch ----------
extern "C" void kernel_launch(void* const* d_in, const int* in_sizes, int n_in,
                              void* d_out, int out_size, void* d_ws, size_t ws_size,
                              hipStream_t stream) {
    const float* x = (const float*)d_in[0];
    const float* y = (const float*)d_in[1];
    float* out = (float*)d_out;
    char* ws = (char*)d_ws;

    float* mu               = (float*)(ws + 0);                   // 1 KiB
    float* cxsum            = (float*)(ws + 1024);                // 16 B
    float* partial2         = (float*)(ws + 65536);               // 1 MiB
    unsigned short* Xn      = (unsigned short*)(ws + 2097152);    // 8 MiB
    unsigned short* Yn      = (unsigned short*)(ws + 10485760);   // 8 MiB
    unsigned short* partial = (unsigned short*)(ws + 2097152);    // 16 MiB bf16 (aliases Xn+Yn, used after gemm)
    unsigned short* Cos     = (unsigned short*)(ws + 18874368);   // 128 MiB

    mu_kernel<<<C, 256, 0, stream>>>(y, mu);
    prep_kernel<<<NROWS / TP, 256, 0, stream>>>(x, y, mu, Xn, Yn);
    gemm_cos<<<dim3(HW / 128, HW / 128, NB), 256, 0, stream>>>(Xn, Yn, Cos);
    rowcol<<<dim3(512, NB), 256, 0, stream>>>(Cos, partial);
    colmax1<<<dim3(2, 16, NB), 256, 0, stream>>>(partial, partial2);
    colfinal2<<<NB, 1024, 0, stream>>>(partial2, cxsum);
    finalize<<<1, 64, 0, stream>>>(cxsum, out);
}